// Round 3
// baseline (337.643 us; speedup 1.0000x reference)
//
#include <hip/hip_runtime.h>
#include <hip/hip_bf16.h>
#include <math.h>

#define BB 64
#define TT 1024
#define NTYPE 16
#define NNODE 256
#define KCAP 512   // compacted masked rows per batch (expected ~192, hard cap)

// ws layout (bytes):
//   0      : acc[8] floats {type_ce, mask_sum, ce_a, ce_b, val, selfloop_dot, dup, spare}
//   32     : s0[64] floats (per-batch gnd sums, node 0)
//   288    : s1[64] floats (per-batch gnd sums, node 1)
//   1024   : cnt[64] ints  (compacted masked-row count per batch)
//   4096   : ec  [64][256][256] f32   (16 MB)
//   +16M   : ma  [64][KCAP][256] bf16 (16 MB)  compacted p_a rows (masked only)
//   +32M   : pb  [64][KCAP][256] bf16 (16 MB)  compacted p_b rows
#define EC_OFF   4096
#define MA_OFF   (EC_OFF + 64ll*256*256*4)
#define PB_OFF   (MA_OFF + 64ll*KCAP*256*2)

__device__ __forceinline__ float wsum(float v) {
    for (int o = 32; o > 0; o >>= 1) v += __shfl_xor(v, o);
    return v;
}
__device__ __forceinline__ float wmax(float v) {
    for (int o = 32; o > 0; o >>= 1) v = fmaxf(v, __shfl_xor(v, o));
    return v;
}
__device__ __forceinline__ unsigned short f2bf(float f) {
    union { float f; unsigned u; } x; x.f = f;
    unsigned r = x.u + 0x7fffu + ((x.u >> 16) & 1u);
    return (unsigned short)(r >> 16);
}
__device__ __forceinline__ float bflo(unsigned u) {  // low bf16 of packed u32 -> f32
    union { unsigned u; float f; } x; x.u = u << 16; return x.f;
}
__device__ __forceinline__ float bfhi(unsigned u) {
    union { unsigned u; float f; } x; x.u = u & 0xffff0000u; return x.f;
}

// One wave (64 lanes) per (b,t) row. 4 waves per block.
__global__ __launch_bounds__(256) void stats_kernel(
    const float* __restrict__ tl, const float* __restrict__ al,
    const float* __restrict__ bl, const float* __restrict__ vals,
    const float* __restrict__ seq,
    float* __restrict__ acc, float* __restrict__ s0, float* __restrict__ s1,
    int* __restrict__ cnt,
    unsigned short* __restrict__ ma, unsigned short* __restrict__ pb)
{
    const int wid  = threadIdx.x >> 6;
    const int lane = threadIdx.x & 63;
    const long row = (long)blockIdx.x * 4 + wid;   // 0..65535
    const int b = (int)(row >> 10);
    const int t = (int)(row & 1023);

    // shifted targets: sequence[b][t+1][:] or zeros at t = T-1
    float4 tgt = make_float4(0.f, 0.f, 0.f, 0.f);
    if (t < TT - 1) tgt = *(const float4*)(seq + (row + 1) * 4);
    const int   t_type = (int)tgt.x;
    const int   t_a    = (int)tgt.y;
    const int   t_b    = (int)tgt.z;
    const float t_val  = tgt.w;
    const float mask   = (t_type >= 3 && t_type <= 5) ? 1.f : 0.f;

    // ---- type softmax / CE / p_comp (16 classes across lanes 0..15) ----
    float tlv = (lane < NTYPE) ? tl[row * NTYPE + lane] : -1e30f;
    float tmx = wmax(tlv);
    float te  = (lane < NTYPE) ? __expf(tlv - tmx) : 0.f;
    float tsum = wsum(te);
    float tcs  = wsum((lane >= 3 && lane <= 5) ? te : 0.f);
    float p_comp = tcs / tsum;
    float ce_type = __logf(tsum) + tmx - __shfl(tlv, t_type);

    // ---- node a softmax (256 across 64 lanes x 4) ----
    float4 av = *(const float4*)(al + row * NNODE + lane * 4);
    float amx = wmax(fmaxf(fmaxf(av.x, av.y), fmaxf(av.z, av.w)));
    float ae0 = __expf(av.x - amx), ae1 = __expf(av.y - amx);
    float ae2 = __expf(av.z - amx), ae3 = __expf(av.w - amx);
    float asum = wsum(ae0 + ae1 + ae2 + ae3);
    float ainv = 1.f / asum;
    float pa0 = ae0 * ainv, pa1 = ae1 * ainv, pa2 = ae2 * ainv, pa3 = ae3 * ainv;
    float asel = ((t_a & 3) == 0) ? av.x : ((t_a & 3) == 1) ? av.y : ((t_a & 3) == 2) ? av.z : av.w;
    float ce_a = __logf(asum) + amx - __shfl(asel, t_a >> 2);

    // ---- node b softmax ----
    float4 bv = *(const float4*)(bl + row * NNODE + lane * 4);
    float bmx = wmax(fmaxf(fmaxf(bv.x, bv.y), fmaxf(bv.z, bv.w)));
    float be0 = __expf(bv.x - bmx), be1 = __expf(bv.y - bmx);
    float be2 = __expf(bv.z - bmx), be3 = __expf(bv.w - bmx);
    float bsum = wsum(be0 + be1 + be2 + be3);
    float binv = 1.f / bsum;
    float pb0 = be0 * binv, pb1 = be1 * binv, pb2 = be2 * binv, pb3 = be3 * binv;
    float bsel = ((t_b & 3) == 0) ? bv.x : ((t_b & 3) == 1) ? bv.y : ((t_b & 3) == 2) ? bv.z : bv.w;
    float ce_b = __logf(bsum) + bmx - __shfl(bsel, t_b >> 2);

    // ---- selfloop dot ----
    float dot = wsum(pa0 * pb0 + pa1 * pb1 + pa2 * pb2 + pa3 * pb3);

    // ---- gnd contributions (unmasked) ----
    float pA0 = __shfl(pa0, 0), pA1 = __shfl(pa1, 0);
    float pB0 = __shfl(pb0, 0), pB1 = __shfl(pb1, 0);
    float s0c = (pA0 + pB0) * p_comp;
    float s1c = (pA1 + pB1) * p_comp;

    // ---- value loss ----
    float pv = vals[row];
    float vloss = mask * (pv - t_val) * (pv - t_val);

    // ---- compacted bf16 prob rows for the ec GEMM ----
    if (mask > 0.f) {
        int slot = 0;
        if (lane == 0) slot = atomicAdd(&cnt[b], 1);
        slot = __shfl(slot, 0);
        if (slot < KCAP) {
            size_t base = (((size_t)b * KCAP + slot) * NNODE) + lane * 4;
            ushort4 wa, wb;
            wa.x = f2bf(pa0); wa.y = f2bf(pa1); wa.z = f2bf(pa2); wa.w = f2bf(pa3);
            wb.x = f2bf(pb0); wb.y = f2bf(pb1); wb.z = f2bf(pb2); wb.w = f2bf(pb3);
            *(ushort4*)(ma + base) = wa;
            *(ushort4*)(pb + base) = wb;
        }
    }

    // ---- block reduction of 8 scalars, one atomic each ----
    __shared__ float red[4][8];
    if (lane == 0) {
        red[wid][0] = ce_type;
        red[wid][1] = mask;
        red[wid][2] = mask * ce_a;
        red[wid][3] = mask * ce_b;
        red[wid][4] = vloss;
        red[wid][5] = mask * dot;
        red[wid][6] = s0c;
        red[wid][7] = s1c;
    }
    __syncthreads();
    if (threadIdx.x < 8) {
        float v = red[0][threadIdx.x] + red[1][threadIdx.x] + red[2][threadIdx.x] + red[3][threadIdx.x];
        if (threadIdx.x == 6)      atomicAdd(&s0[b], v);
        else if (threadIdx.x == 7) atomicAdd(&s1[b], v);
        else                       atomicAdd(&acc[threadIdx.x], v);
    }
}

// Batched ec GEMM over compacted K: ec[b][i][j] = sum_k ma[b][k][i] * pb[b][k][j]
// VALU f32 outer-product; [k][m] storage is the natural layout for this tiling.
#define BK 32
__global__ __launch_bounds__(256) void ec_gemm(
    const unsigned short* __restrict__ ma, const unsigned short* __restrict__ pb,
    const int* __restrict__ cnt, float* __restrict__ ec)
{
    const int b = blockIdx.y;
    int K = cnt[b];
    if (K > KCAP) K = KCAP;
    const int ti = (blockIdx.x >> 2) * 64;
    const int tj = (blockIdx.x & 3) * 64;
    __shared__ unsigned short As[BK][64];
    __shared__ unsigned short Bs[BK][64];
    const int tid = threadIdx.x;
    const int lr = tid >> 3;          // staging row 0..31
    const int lc = (tid & 7) * 8;     // staging col 0..56
    const int tx = tid & 15, ty = tid >> 4;
    const size_t bb = (size_t)b * KCAP * NNODE;
    float c[4][4] = {};

    for (int k0 = 0; k0 < K; k0 += BK) {
        int kr = k0 + lr;
        uint4 va = make_uint4(0, 0, 0, 0), vb = make_uint4(0, 0, 0, 0);
        if (kr < K) {
            va = *(const uint4*)(ma + bb + (size_t)kr * NNODE + ti + lc);
            vb = *(const uint4*)(pb + bb + (size_t)kr * NNODE + tj + lc);
        }
        __syncthreads();
        *(uint4*)&As[lr][lc] = va;
        *(uint4*)&Bs[lr][lc] = vb;
        __syncthreads();
        for (int kk = 0; kk < BK; ++kk) {
            uint2 ua = *(const uint2*)&As[kk][ty * 4];
            uint2 ub = *(const uint2*)&Bs[kk][tx * 4];
            float a0 = bflo(ua.x), a1 = bfhi(ua.x), a2 = bflo(ua.y), a3 = bfhi(ua.y);
            float b0 = bflo(ub.x), b1 = bfhi(ub.x), b2 = bflo(ub.y), b3 = bfhi(ub.y);
            c[0][0] += a0 * b0; c[0][1] += a0 * b1; c[0][2] += a0 * b2; c[0][3] += a0 * b3;
            c[1][0] += a1 * b0; c[1][1] += a1 * b1; c[1][2] += a1 * b2; c[1][3] += a1 * b3;
            c[2][0] += a2 * b0; c[2][1] += a2 * b1; c[2][2] += a2 * b2; c[2][3] += a2 * b3;
            c[3][0] += a3 * b0; c[3][1] += a3 * b1; c[3][2] += a3 * b2; c[3][3] += a3 * b3;
        }
    }
    float* outp = ec + ((size_t)b << 16);
    for (int r = 0; r < 4; ++r) {
        int i = ti + ty * 4 + r;
        *(float4*)(outp + (size_t)i * NNODE + tj + tx * 4) =
            make_float4(c[r][0], c[r][1], c[r][2], c[r][3]);
    }
}

__global__ __launch_bounds__(256) void dup_kernel(const float* __restrict__ ec,
                                                  float* __restrict__ acc)
{
    const long n = 64l * 256 * 256;
    float s = 0.f;
    for (long idx = (long)blockIdx.x * 256 + threadIdx.x; idx < n;
         idx += (long)gridDim.x * 256) {
        int b = (int)(idx >> 16);
        int i = (int)((idx >> 8) & 255);
        int j = (int)(idx & 255);
        float x = ec[idx];
        float y = ec[((long)b << 16) + ((long)j << 8) + i];
        float r = x + y - 1.f;
        if (r > 0.f) s += r * r;
    }
    s = wsum(s);
    __shared__ float red[4];
    if ((threadIdx.x & 63) == 0) red[threadIdx.x >> 6] = s;
    __syncthreads();
    if (threadIdx.x == 0) atomicAdd(acc + 6, red[0] + red[1] + red[2] + red[3]);
}

__global__ void finalize_kernel(const float* __restrict__ acc,
                                const float* __restrict__ s0,
                                const float* __restrict__ s1,
                                float* __restrict__ out)
{
    const int lane = threadIdx.x;  // 64 threads = 1 wave
    float e0 = __expf(-s0[lane]);
    float e1 = __expf(-s1[lane]);
    float g = wsum(e0) * (1.f / 64.f) + wsum(e1) * (1.f / 64.f);
    if (lane == 0) {
        float denom = acc[1] + 1e-8f;
        float type_loss = acc[0] / 65536.f;
        float node = 0.5f * (acc[2] / denom + acc[3] / denom);
        float value = acc[4] / denom;
        float self = acc[5] / denom;
        float dup = acc[6] / (64.f * 256.f * 256.f);
        out[0] = 1.0f * type_loss + 0.5f * node + 1.0f * value
               + 2.0f * self + 1.0f * dup + 0.5f * g;
    }
}

extern "C" void kernel_launch(void* const* d_in, const int* in_sizes, int n_in,
                              void* d_out, int out_size, void* d_ws, size_t ws_size,
                              hipStream_t stream)
{
    const float* tl   = (const float*)d_in[0];
    const float* al   = (const float*)d_in[1];
    const float* bl   = (const float*)d_in[2];
    const float* vals = (const float*)d_in[3];
    const float* seq  = (const float*)d_in[4];

    char* ws = (char*)d_ws;
    float* acc = (float*)ws;
    float* s0  = (float*)(ws + 32);
    float* s1  = (float*)(ws + 288);
    int*   cnt = (int*)(ws + 1024);
    float* ec  = (float*)(ws + EC_OFF);
    unsigned short* ma = (unsigned short*)(ws + MA_OFF);
    unsigned short* pb = (unsigned short*)(ws + PB_OFF);

    hipMemsetAsync(ws, 0, 4096, stream);  // zero acc/s0/s1/cnt each call

    stats_kernel<<<16384, 256, 0, stream>>>(tl, al, bl, vals, seq,
                                            acc, s0, s1, cnt, ma, pb);
    dim3 gg(16, 64);
    ec_gemm<<<gg, 256, 0, stream>>>(ma, pb, cnt, ec);
    dup_kernel<<<4096, 256, 0, stream>>>(ec, acc);
    finalize_kernel<<<1, 64, 0, stream>>>(acc, s0, s1, (float*)d_out);
}

// Round 4
// 203.920 us; speedup vs baseline: 1.6558x; 1.6558x over previous
//
#include <hip/hip_runtime.h>
#include <hip/hip_bf16.h>
#include <math.h>

#define BB 64
#define TT 1024
#define NTYPE 16
#define NNODE 256
#define KCAP 512   // compacted masked rows per batch (expected ~192, hard cap)

// ws layout (bytes):
//   0        : cnt[64] ints  (compaction counters; zeroed each launch)
//   4096     : part [16384][8] f32  (per-block partials from stats)      512 KB
//   528384   : bpart[64][8]   f32  (per-batch sums)                      2 KB
//   532480   : dpart[1024]    f32  (dup partials)                        4 KB
//   1048576  : ec  [64][256][256] f32                                    16 MB
//   +16M     : ma  [64][KCAP][256] bf16 (compacted p_a rows)             16 MB
//   +32M     : pb  [64][KCAP][256] bf16 (compacted p_b rows)             16 MB
#define PART_OFF  4096
#define BPART_OFF 528384
#define DPART_OFF 532480
#define EC_OFF    1048576ll
#define MA_OFF    (EC_OFF + 64ll*256*256*4)
#define PB_OFF    (MA_OFF + 64ll*KCAP*256*2)

__device__ __forceinline__ float wsum(float v) {
    for (int o = 32; o > 0; o >>= 1) v += __shfl_xor(v, o);
    return v;
}
__device__ __forceinline__ float wmax(float v) {
    for (int o = 32; o > 0; o >>= 1) v = fmaxf(v, __shfl_xor(v, o));
    return v;
}
__device__ __forceinline__ unsigned short f2bf(float f) {
    union { float f; unsigned u; } x; x.f = f;
    unsigned r = x.u + 0x7fffu + ((x.u >> 16) & 1u);
    return (unsigned short)(r >> 16);
}
__device__ __forceinline__ float bflo(unsigned u) {
    union { unsigned u; float f; } x; x.u = u << 16; return x.f;
}
__device__ __forceinline__ float bfhi(unsigned u) {
    union { unsigned u; float f; } x; x.u = u & 0xffff0000u; return x.f;
}

// One wave (64 lanes) per (b,t) row. 4 waves per block. NO global accumulation atomics.
__global__ __launch_bounds__(256) void stats_kernel(
    const float* __restrict__ tl, const float* __restrict__ al,
    const float* __restrict__ bl, const float* __restrict__ vals,
    const float* __restrict__ seq,
    int* __restrict__ cnt, float* __restrict__ part,
    unsigned short* __restrict__ ma, unsigned short* __restrict__ pb)
{
    const int wid  = threadIdx.x >> 6;
    const int lane = threadIdx.x & 63;
    const long row = (long)blockIdx.x * 4 + wid;   // 0..65535
    const int b = (int)(row >> 10);
    const int t = (int)(row & 1023);

    // shifted targets: sequence[b][t+1][:] or zeros at t = T-1
    float4 tgt = make_float4(0.f, 0.f, 0.f, 0.f);
    if (t < TT - 1) tgt = *(const float4*)(seq + (row + 1) * 4);
    const int   t_type = (int)tgt.x;
    const int   t_a    = (int)tgt.y;
    const int   t_b    = (int)tgt.z;
    const float t_val  = tgt.w;
    const float mask   = (t_type >= 3 && t_type <= 5) ? 1.f : 0.f;

    // compaction slot: issue the (return-value) atomic EARLY so its latency
    // overlaps the softmax computation; the dependent __shfl happens at the end.
    int slot0 = 0;
    if (mask > 0.f && lane == 0) slot0 = atomicAdd(&cnt[b], 1);

    // ---- type softmax / CE / p_comp (16 classes across lanes 0..15) ----
    float tlv = (lane < NTYPE) ? tl[row * NTYPE + lane] : -1e30f;
    float tmx = wmax(tlv);
    float te  = (lane < NTYPE) ? __expf(tlv - tmx) : 0.f;
    float tsum = wsum(te);
    float tcs  = wsum((lane >= 3 && lane <= 5) ? te : 0.f);
    float p_comp = tcs / tsum;
    float ce_type = __logf(tsum) + tmx - __shfl(tlv, t_type);

    // ---- node a softmax (256 across 64 lanes x 4) ----
    float4 av = *(const float4*)(al + row * NNODE + lane * 4);
    float amx = wmax(fmaxf(fmaxf(av.x, av.y), fmaxf(av.z, av.w)));
    float ae0 = __expf(av.x - amx), ae1 = __expf(av.y - amx);
    float ae2 = __expf(av.z - amx), ae3 = __expf(av.w - amx);
    float asum = wsum(ae0 + ae1 + ae2 + ae3);
    float ainv = 1.f / asum;
    float pa0 = ae0 * ainv, pa1 = ae1 * ainv, pa2 = ae2 * ainv, pa3 = ae3 * ainv;
    float asel = ((t_a & 3) == 0) ? av.x : ((t_a & 3) == 1) ? av.y : ((t_a & 3) == 2) ? av.z : av.w;
    float ce_a = __logf(asum) + amx - __shfl(asel, t_a >> 2);

    // ---- node b softmax ----
    float4 bv = *(const float4*)(bl + row * NNODE + lane * 4);
    float bmx = wmax(fmaxf(fmaxf(bv.x, bv.y), fmaxf(bv.z, bv.w)));
    float be0 = __expf(bv.x - bmx), be1 = __expf(bv.y - bmx);
    float be2 = __expf(bv.z - bmx), be3 = __expf(bv.w - bmx);
    float bsum = wsum(be0 + be1 + be2 + be3);
    float binv = 1.f / bsum;
    float pb0 = be0 * binv, pb1 = be1 * binv, pb2 = be2 * binv, pb3 = be3 * binv;
    float bsel = ((t_b & 3) == 0) ? bv.x : ((t_b & 3) == 1) ? bv.y : ((t_b & 3) == 2) ? bv.z : bv.w;
    float ce_b = __logf(bsum) + bmx - __shfl(bsel, t_b >> 2);

    // ---- selfloop dot ----
    float dot = wsum(pa0 * pb0 + pa1 * pb1 + pa2 * pb2 + pa3 * pb3);

    // ---- gnd contributions (unmasked) ----
    float pA0 = __shfl(pa0, 0), pA1 = __shfl(pa1, 0);
    float pB0 = __shfl(pb0, 0), pB1 = __shfl(pb1, 0);
    float s0c = (pA0 + pB0) * p_comp;
    float s1c = (pA1 + pB1) * p_comp;

    // ---- value loss ----
    float pv = vals[row];
    float vloss = mask * (pv - t_val) * (pv - t_val);

    // ---- compacted bf16 prob rows for the ec GEMM ----
    if (mask > 0.f) {
        int slot = __shfl(slot0, 0);
        if (slot < KCAP) {
            size_t base = (((size_t)b * KCAP + slot) * NNODE) + lane * 4;
            ushort4 wa, wb;
            wa.x = f2bf(pa0); wa.y = f2bf(pa1); wa.z = f2bf(pa2); wa.w = f2bf(pa3);
            wb.x = f2bf(pb0); wb.y = f2bf(pb1); wb.z = f2bf(pb2); wb.w = f2bf(pb3);
            *(ushort4*)(ma + base) = wa;
            *(ushort4*)(pb + base) = wb;
        }
    }

    // ---- block reduction of 8 scalars -> plain store of per-block partials ----
    __shared__ float red[4][8];
    if (lane == 0) {
        red[wid][0] = ce_type;
        red[wid][1] = mask;
        red[wid][2] = mask * ce_a;
        red[wid][3] = mask * ce_b;
        red[wid][4] = vloss;
        red[wid][5] = mask * dot;
        red[wid][6] = s0c;
        red[wid][7] = s1c;
    }
    __syncthreads();
    if (threadIdx.x < 8) {
        part[(size_t)blockIdx.x * 8 + threadIdx.x] =
            red[0][threadIdx.x] + red[1][threadIdx.x] +
            red[2][threadIdx.x] + red[3][threadIdx.x];
    }
}

// 64 blocks, one per batch: sum the 256 stats-block partials of that batch.
__global__ __launch_bounds__(256) void reduce_kernel(const float* __restrict__ part,
                                                     float* __restrict__ bpart)
{
    const int b = blockIdx.x;
    const float* p = part + ((size_t)b * 256 + threadIdx.x) * 8;
    float v[8];
#pragma unroll
    for (int k = 0; k < 8; ++k) v[k] = p[k];
#pragma unroll
    for (int k = 0; k < 8; ++k) v[k] = wsum(v[k]);
    __shared__ float red[4][8];
    const int wid = threadIdx.x >> 6, lane = threadIdx.x & 63;
    if (lane == 0) {
#pragma unroll
        for (int k = 0; k < 8; ++k) red[wid][k] = v[k];
    }
    __syncthreads();
    if (threadIdx.x < 8) {
        bpart[b * 8 + threadIdx.x] =
            red[0][threadIdx.x] + red[1][threadIdx.x] +
            red[2][threadIdx.x] + red[3][threadIdx.x];
    }
}

// Batched ec GEMM over compacted K: ec[b][i][j] = sum_k ma[b][k][i] * pb[b][k][j]
#define BK 32
__global__ __launch_bounds__(256) void ec_gemm(
    const unsigned short* __restrict__ ma, const unsigned short* __restrict__ pb,
    const int* __restrict__ cnt, float* __restrict__ ec)
{
    const int b = blockIdx.y;
    int K = cnt[b];
    if (K > KCAP) K = KCAP;
    const int ti = (blockIdx.x >> 2) * 64;
    const int tj = (blockIdx.x & 3) * 64;
    __shared__ unsigned short As[BK][64];
    __shared__ unsigned short Bs[BK][64];
    const int tid = threadIdx.x;
    const int lr = tid >> 3;          // staging row 0..31
    const int lc = (tid & 7) * 8;     // staging col 0..56
    const int tx = tid & 15, ty = tid >> 4;
    const size_t bb = (size_t)b * KCAP * NNODE;
    float c[4][4] = {};

    for (int k0 = 0; k0 < K; k0 += BK) {
        int kr = k0 + lr;
        uint4 va = make_uint4(0, 0, 0, 0), vb = make_uint4(0, 0, 0, 0);
        if (kr < K) {
            va = *(const uint4*)(ma + bb + (size_t)kr * NNODE + ti + lc);
            vb = *(const uint4*)(pb + bb + (size_t)kr * NNODE + tj + lc);
        }
        __syncthreads();
        *(uint4*)&As[lr][lc] = va;
        *(uint4*)&Bs[lr][lc] = vb;
        __syncthreads();
        for (int kk = 0; kk < BK; ++kk) {
            uint2 ua = *(const uint2*)&As[kk][ty * 4];
            uint2 ub = *(const uint2*)&Bs[kk][tx * 4];
            float a0 = bflo(ua.x), a1 = bfhi(ua.x), a2 = bflo(ua.y), a3 = bfhi(ua.y);
            float b0 = bflo(ub.x), b1 = bfhi(ub.x), b2 = bflo(ub.y), b3 = bfhi(ub.y);
            c[0][0] += a0 * b0; c[0][1] += a0 * b1; c[0][2] += a0 * b2; c[0][3] += a0 * b3;
            c[1][0] += a1 * b0; c[1][1] += a1 * b1; c[1][2] += a1 * b2; c[1][3] += a1 * b3;
            c[2][0] += a2 * b0; c[2][1] += a2 * b1; c[2][2] += a2 * b2; c[2][3] += a2 * b3;
            c[3][0] += a3 * b0; c[3][1] += a3 * b1; c[3][2] += a3 * b2; c[3][3] += a3 * b3;
        }
    }
    float* outp = ec + ((size_t)b << 16);
    for (int r = 0; r < 4; ++r) {
        int i = ti + ty * 4 + r;
        *(float4*)(outp + (size_t)i * NNODE + tj + tx * 4) =
            make_float4(c[r][0], c[r][1], c[r][2], c[r][3]);
    }
}

__global__ __launch_bounds__(256) void dup_kernel(const float* __restrict__ ec,
                                                  float* __restrict__ dpart)
{
    const long n = 64l * 256 * 256;
    float s = 0.f;
    for (long idx = (long)blockIdx.x * 256 + threadIdx.x; idx < n;
         idx += (long)gridDim.x * 256) {
        int b = (int)(idx >> 16);
        int i = (int)((idx >> 8) & 255);
        int j = (int)(idx & 255);
        float x = ec[idx];
        float y = ec[((long)b << 16) + ((long)j << 8) + i];
        float r = x + y - 1.f;
        if (r > 0.f) s += r * r;
    }
    s = wsum(s);
    __shared__ float red[4];
    if ((threadIdx.x & 63) == 0) red[threadIdx.x >> 6] = s;
    __syncthreads();
    if (threadIdx.x == 0) dpart[blockIdx.x] = red[0] + red[1] + red[2] + red[3];
}

__global__ void finalize_kernel(const float* __restrict__ bpart,
                                const float* __restrict__ dpart,
                                float* __restrict__ out)
{
    const int lane = threadIdx.x;  // 64 threads = 1 wave; lane == batch index
    float v[8];
#pragma unroll
    for (int k = 0; k < 8; ++k) v[k] = bpart[lane * 8 + k];
    float tot_ce   = wsum(v[0]);
    float tot_mask = wsum(v[1]);
    float tot_cea  = wsum(v[2]);
    float tot_ceb  = wsum(v[3]);
    float tot_val  = wsum(v[4]);
    float tot_dot  = wsum(v[5]);
    float g = wsum(__expf(-v[6]) + __expf(-v[7])) * (1.f / 64.f);
    float d = 0.f;
#pragma unroll
    for (int i = 0; i < 16; ++i) d += dpart[lane + 64 * i];
    float dsum = wsum(d);
    if (lane == 0) {
        float denom = tot_mask + 1e-8f;
        float type_loss = tot_ce / 65536.f;
        float node = 0.5f * (tot_cea / denom + tot_ceb / denom);
        float value = tot_val / denom;
        float self = tot_dot / denom;
        float dup = dsum / (64.f * 256.f * 256.f);
        out[0] = 1.0f * type_loss + 0.5f * node + 1.0f * value
               + 2.0f * self + 1.0f * dup + 0.5f * g;
    }
}

extern "C" void kernel_launch(void* const* d_in, const int* in_sizes, int n_in,
                              void* d_out, int out_size, void* d_ws, size_t ws_size,
                              hipStream_t stream)
{
    const float* tl   = (const float*)d_in[0];
    const float* al   = (const float*)d_in[1];
    const float* bl   = (const float*)d_in[2];
    const float* vals = (const float*)d_in[3];
    const float* seq  = (const float*)d_in[4];

    char* ws = (char*)d_ws;
    int*   cnt   = (int*)ws;
    float* part  = (float*)(ws + PART_OFF);
    float* bpart = (float*)(ws + BPART_OFF);
    float* dpart = (float*)(ws + DPART_OFF);
    float* ec    = (float*)(ws + EC_OFF);
    unsigned short* ma = (unsigned short*)(ws + MA_OFF);
    unsigned short* pb = (unsigned short*)(ws + PB_OFF);

    hipMemsetAsync(cnt, 0, 256, stream);  // zero compaction counters each call

    stats_kernel<<<16384, 256, 0, stream>>>(tl, al, bl, vals, seq,
                                            cnt, part, ma, pb);
    reduce_kernel<<<64, 256, 0, stream>>>(part, bpart);
    dim3 gg(16, 64);
    ec_gemm<<<gg, 256, 0, stream>>>(ma, pb, cnt, ec);
    dup_kernel<<<1024, 256, 0, stream>>>(ec, dpart);
    finalize_kernel<<<1, 64, 0, stream>>>(bpart, dpart, (float*)d_out);
}

// Round 5
// 90.676 us; speedup vs baseline: 3.7236x; 2.2489x over previous
//
#include <hip/hip_runtime.h>
#include <hip/hip_bf16.h>
#include <math.h>

#define TT 1024
#define NTYPE 16
#define NNODE 256
#define KCAP 512   // compacted masked rows per batch (expected ~192; 26 sigma headroom)

// ws layout (bytes):
//   0        : cnt[64] int
//   1024     : slotmap[64][1024] short          128 KB
//   132096   : part[4096][8] f32                128 KB
//   263168   : bpart[64][8] f32                 2 KB
//   265216   : dpart[64][10] f32                2.5 KB
//   1048576  : ma [64][KCAP][256] bf16          16 MB
//   +16M     : pb [64][KCAP][256] bf16          16 MB
#define SLOT_OFF  1024
#define PART_OFF  132096
#define BPART_OFF 263168
#define DPART_OFF 265216
#define MA_OFF    1048576ll
#define PB_OFF    (MA_OFF + 64ll*KCAP*256*2)

__device__ __forceinline__ float wsum(float v) {
    for (int o = 32; o > 0; o >>= 1) v += __shfl_xor(v, o);
    return v;
}
__device__ __forceinline__ float gsum(float v) {   // 16-lane group sum
    v += __shfl_xor(v, 8); v += __shfl_xor(v, 4);
    v += __shfl_xor(v, 2); v += __shfl_xor(v, 1);
    return v;
}
__device__ __forceinline__ float gmax(float v) {   // 16-lane group max
    v = fmaxf(v, __shfl_xor(v, 8)); v = fmaxf(v, __shfl_xor(v, 4));
    v = fmaxf(v, __shfl_xor(v, 2)); v = fmaxf(v, __shfl_xor(v, 1));
    return v;
}
__device__ __forceinline__ unsigned short f2bf(float f) {
    union { float f; unsigned u; } x; x.f = f;
    unsigned r = x.u + 0x7fffu + ((x.u >> 16) & 1u);
    return (unsigned short)(r >> 16);
}
__device__ __forceinline__ float bflo(unsigned u) {
    union { unsigned u; float f; } x; x.u = u << 16; return x.f;
}
__device__ __forceinline__ float bfhi(unsigned u) {
    union { unsigned u; float f; } x; x.u = u & 0xffff0000u; return x.f;
}
__device__ __forceinline__ float sel4(float4 v, int e) {
    float x = (e & 1) ? v.y : v.x;
    float y = (e & 1) ? v.w : v.z;
    return (e & 2) ? y : x;
}
__device__ __forceinline__ float sel16(float4 v0, float4 v1, float4 v2, float4 v3,
                                       int j, int e) {
    float s0 = sel4(v0, e), s1 = sel4(v1, e), s2 = sel4(v2, e), s3 = sel4(v3, e);
    float c01 = (j & 1) ? s1 : s0;
    float c23 = (j & 1) ? s3 : s2;
    return (j & 2) ? c23 : c01;
}
__device__ __forceinline__ float max16(float4 a0, float4 a1, float4 a2, float4 a3) {
    float m0 = fmaxf(fmaxf(a0.x, a0.y), fmaxf(a0.z, a0.w));
    float m1 = fmaxf(fmaxf(a1.x, a1.y), fmaxf(a1.z, a1.w));
    float m2 = fmaxf(fmaxf(a2.x, a2.y), fmaxf(a2.z, a2.w));
    float m3 = fmaxf(fmaxf(a3.x, a3.y), fmaxf(a3.z, a3.w));
    return fmaxf(fmaxf(m0, m1), fmaxf(m2, m3));
}

// ---- deterministic compaction slots: per-batch prefix sum of the mask ----
__global__ __launch_bounds__(256) void scan_kernel(const float* __restrict__ seq,
                                                   int* __restrict__ cnt,
                                                   short* __restrict__ slotmap)
{
    const int b = blockIdx.x;
    const int tid = threadIdx.x;
    const int lane = tid & 63, w = tid >> 6;
    const int t0 = tid * 4;
    int m0 = 0, m1 = 0, m2 = 0, m3 = 0;
    {
        int tt;
        tt = (int)seq[((size_t)b * TT + t0 + 1) * 4];               m0 = (tt >= 3 && tt <= 5);
        tt = (int)seq[((size_t)b * TT + t0 + 2) * 4];               m1 = (tt >= 3 && tt <= 5);
        tt = (int)seq[((size_t)b * TT + t0 + 3) * 4];               m2 = (tt >= 3 && tt <= 5);
        if (t0 + 3 < TT - 1) {
            tt = (int)seq[((size_t)b * TT + t0 + 4) * 4];           m3 = (tt >= 3 && tt <= 5);
        }
    }
    int lc = m0 + m1 + m2 + m3;
    int inc = lc;
    for (int o = 1; o < 64; o <<= 1) {
        int v = __shfl_up(inc, o);
        if (lane >= o) inc += v;
    }
    __shared__ int wtot[4];
    if (lane == 63) wtot[w] = inc;
    __syncthreads();
    int woff = 0;
    for (int i = 0; i < 4; ++i) woff += (i < w) ? wtot[i] : 0;
    int run = woff + inc - lc;
    if (m0) { slotmap[(size_t)b * TT + t0 + 0] = (short)run; ++run; }
    if (m1) { slotmap[(size_t)b * TT + t0 + 1] = (short)run; ++run; }
    if (m2) { slotmap[(size_t)b * TT + t0 + 2] = (short)run; ++run; }
    if (m3) { slotmap[(size_t)b * TT + t0 + 3] = (short)run; ++run; }
    if (tid == 255) cnt[b] = woff + inc;
}

// ---- fused per-row stats: 16-lane group per row, 4 rows per wave ----
__global__ __launch_bounds__(256) void stats_kernel(
    const float* __restrict__ tl, const float* __restrict__ al,
    const float* __restrict__ bl, const float* __restrict__ vals,
    const float* __restrict__ seq, const short* __restrict__ slotmap,
    float* __restrict__ part,
    unsigned short* __restrict__ ma, unsigned short* __restrict__ pb)
{
    const int tid = threadIdx.x;
    const int w = tid >> 6, lane = tid & 63;
    const int s = lane & 15;                       // sublane within 16-lane group
    const int rowbase = blockIdx.x * 16 + w * 4;
    const int row = rowbase + (lane >> 4);
    const int b = row >> 10, t = row & 1023;

    // shifted target (group-uniform)
    float4 tgt = make_float4(0.f, 0.f, 0.f, 0.f);
    if (t < TT - 1) tgt = *(const float4*)(seq + (size_t)(row + 1) * 4);
    const int   t_type = (int)tgt.x;
    const int   t_a    = (int)tgt.y;
    const int   t_b    = (int)tgt.z;
    const float t_val  = tgt.w;
    const float mask   = (t_type >= 3 && t_type <= 5) ? 1.f : 0.f;

    // ---- type softmax: exactly 1 logit per sublane ----
    float tlv = tl[(size_t)rowbase * 16 + lane];
    float tmx = gmax(tlv);
    float te  = __expf(tlv - tmx);
    float tsum = gsum(te);
    float tcs  = gsum((s >= 3 && s <= 5) ? te : 0.f);
    float p_comp = tcs / tsum;
    float ce_type = __logf(tsum) + tmx - __shfl(tlv, (lane & 48) + t_type);

    // ---- node a: 16 logits per sublane (4 x float4, stride-64 chunks) ----
    const float* arow = al + (size_t)row * 256;
    float4 a0 = *(const float4*)(arow + s * 4);
    float4 a1 = *(const float4*)(arow + s * 4 + 64);
    float4 a2 = *(const float4*)(arow + s * 4 + 128);
    float4 a3 = *(const float4*)(arow + s * 4 + 192);
    const float* brow = bl + (size_t)row * 256;
    float4 b0 = *(const float4*)(brow + s * 4);
    float4 b1 = *(const float4*)(brow + s * 4 + 64);
    float4 b2 = *(const float4*)(brow + s * 4 + 128);
    float4 b3 = *(const float4*)(brow + s * 4 + 192);

    // CE gathers on raw logits (issued early; independent of reductions)
    const int ja = t_a >> 6, sa = (t_a >> 2) & 15, ea = t_a & 3;
    const int jb = t_b >> 6, sb = (t_b >> 2) & 15, eb = t_b & 3;
    float ga = __shfl(sel16(a0, a1, a2, a3, ja, ea), (lane & 48) + sa);
    float gb = __shfl(sel16(b0, b1, b2, b3, jb, eb), (lane & 48) + sb);

    float amx = gmax(max16(a0, a1, a2, a3));
    float bmx = gmax(max16(b0, b1, b2, b3));

    float ea0x = __expf(a0.x - amx), ea0y = __expf(a0.y - amx), ea0z = __expf(a0.z - amx), ea0w = __expf(a0.w - amx);
    float ea1x = __expf(a1.x - amx), ea1y = __expf(a1.y - amx), ea1z = __expf(a1.z - amx), ea1w = __expf(a1.w - amx);
    float ea2x = __expf(a2.x - amx), ea2y = __expf(a2.y - amx), ea2z = __expf(a2.z - amx), ea2w = __expf(a2.w - amx);
    float ea3x = __expf(a3.x - amx), ea3y = __expf(a3.y - amx), ea3z = __expf(a3.z - amx), ea3w = __expf(a3.w - amx);
    float eb0x = __expf(b0.x - bmx), eb0y = __expf(b0.y - bmx), eb0z = __expf(b0.z - bmx), eb0w = __expf(b0.w - bmx);
    float eb1x = __expf(b1.x - bmx), eb1y = __expf(b1.y - bmx), eb1z = __expf(b1.z - bmx), eb1w = __expf(b1.w - bmx);
    float eb2x = __expf(b2.x - bmx), eb2y = __expf(b2.y - bmx), eb2z = __expf(b2.z - bmx), eb2w = __expf(b2.w - bmx);
    float eb3x = __expf(b3.x - bmx), eb3y = __expf(b3.y - bmx), eb3z = __expf(b3.z - bmx), eb3w = __expf(b3.w - bmx);

    float lsa = ((ea0x + ea0y) + (ea0z + ea0w)) + ((ea1x + ea1y) + (ea1z + ea1w))
              + ((ea2x + ea2y) + (ea2z + ea2w)) + ((ea3x + ea3y) + (ea3z + ea3w));
    float lsb = ((eb0x + eb0y) + (eb0z + eb0w)) + ((eb1x + eb1y) + (eb1z + eb1w))
              + ((eb2x + eb2y) + (eb2z + eb2w)) + ((eb3x + eb3y) + (eb3z + eb3w));
    float asum = gsum(lsa);
    float bsum = gsum(lsb);
    float ainv = 1.f / asum, binv = 1.f / bsum;

    float ce_a = __logf(asum) + amx - ga;
    float ce_b = __logf(bsum) + bmx - gb;

    // selfloop dot: sum(ea*eb) * ainv * binv
    float dl = ((ea0x * eb0x + ea0y * eb0y) + (ea0z * eb0z + ea0w * eb0w))
             + ((ea1x * eb1x + ea1y * eb1y) + (ea1z * eb1z + ea1w * eb1w))
             + ((ea2x * eb2x + ea2y * eb2y) + (ea2z * eb2z + ea2w * eb2w))
             + ((ea3x * eb3x + ea3y * eb3y) + (ea3z * eb3z + ea3w * eb3w));
    float dot = gsum(dl) * ainv * binv;

    // gnd: p_a[0],p_a[1],p_b[0],p_b[1] live on sublane 0 (elements 0,1)
    float s0c = ((ea0x * ainv) + (eb0x * binv)) * p_comp;
    float s1c = ((ea0y * ainv) + (eb0y * binv)) * p_comp;

    // value loss (group-uniform)
    float pv = vals[row];
    float vloss = mask * (pv - t_val) * (pv - t_val);

    // ---- compacted bf16 prob rows ----
    if (mask > 0.f) {
        int slot = slotmap[row];
        if (slot < KCAP) {
            size_t base = ((size_t)b * KCAP + slot) * 256 + s * 4;
            ushort4 v;
            v.x = f2bf(ea0x * ainv); v.y = f2bf(ea0y * ainv); v.z = f2bf(ea0z * ainv); v.w = f2bf(ea0w * ainv);
            *(ushort4*)(ma + base) = v;
            v.x = f2bf(ea1x * ainv); v.y = f2bf(ea1y * ainv); v.z = f2bf(ea1z * ainv); v.w = f2bf(ea1w * ainv);
            *(ushort4*)(ma + base + 64) = v;
            v.x = f2bf(ea2x * ainv); v.y = f2bf(ea2y * ainv); v.z = f2bf(ea2z * ainv); v.w = f2bf(ea2w * ainv);
            *(ushort4*)(ma + base + 128) = v;
            v.x = f2bf(ea3x * ainv); v.y = f2bf(ea3y * ainv); v.z = f2bf(ea3z * ainv); v.w = f2bf(ea3w * ainv);
            *(ushort4*)(ma + base + 192) = v;
            v.x = f2bf(eb0x * binv); v.y = f2bf(eb0y * binv); v.z = f2bf(eb0z * binv); v.w = f2bf(eb0w * binv);
            *(ushort4*)(pb + base) = v;
            v.x = f2bf(eb1x * binv); v.y = f2bf(eb1y * binv); v.z = f2bf(eb1z * binv); v.w = f2bf(eb1w * binv);
            *(ushort4*)(pb + base + 64) = v;
            v.x = f2bf(eb2x * binv); v.y = f2bf(eb2y * binv); v.z = f2bf(eb2z * binv); v.w = f2bf(eb2w * binv);
            *(ushort4*)(pb + base + 128) = v;
            v.x = f2bf(eb3x * binv); v.y = f2bf(eb3y * binv); v.z = f2bf(eb3z * binv); v.w = f2bf(eb3w * binv);
            *(ushort4*)(pb + base + 192) = v;
        }
    }

    // ---- reduce 8 scalars: group-leader only, then xor16+xor32 across groups ----
    float r0 = (s == 0) ? ce_type       : 0.f;
    float r1 = (s == 0) ? mask          : 0.f;
    float r2 = (s == 0) ? mask * ce_a   : 0.f;
    float r3 = (s == 0) ? mask * ce_b   : 0.f;
    float r4 = (s == 0) ? vloss         : 0.f;
    float r5 = (s == 0) ? mask * dot    : 0.f;
    float r6 = (s == 0) ? s0c           : 0.f;
    float r7 = (s == 0) ? s1c           : 0.f;
#define XR(v) v += __shfl_xor(v, 16); v += __shfl_xor(v, 32);
    XR(r0) XR(r1) XR(r2) XR(r3) XR(r4) XR(r5) XR(r6) XR(r7)
#undef XR
    __shared__ float red[4][8];
    if (lane == 0) {
        red[w][0] = r0; red[w][1] = r1; red[w][2] = r2; red[w][3] = r3;
        red[w][4] = r4; red[w][5] = r5; red[w][6] = r6; red[w][7] = r7;
    }
    __syncthreads();
    if (tid < 8) {
        part[(size_t)blockIdx.x * 8 + tid] =
            red[0][tid] + red[1][tid] + red[2][tid] + red[3][tid];
    }
}

// ---- per-batch reduction of 64 block partials ----
__global__ __launch_bounds__(64) void reduce_kernel(const float* __restrict__ part,
                                                    float* __restrict__ bpart)
{
    const int b = blockIdx.x;
    const float* p = part + ((size_t)b * 64 + threadIdx.x) * 8;
    float v0 = wsum(p[0]), v1 = wsum(p[1]), v2 = wsum(p[2]), v3 = wsum(p[3]);
    float v4 = wsum(p[4]), v5 = wsum(p[5]), v6 = wsum(p[6]), v7 = wsum(p[7]);
    if (threadIdx.x == 0) {
        float* o = bpart + b * 8;
        o[0] = v0; o[1] = v1; o[2] = v2; o[3] = v3;
        o[4] = v4; o[5] = v5; o[6] = v6; o[7] = v7;
    }
}

// ---- fused ec GEMM + dup penalty: 64x64 tile pairs, no ec materialization ----
__constant__ int cTI[10] = {0, 1, 2, 3, 0, 0, 0, 1, 1, 2};
__constant__ int cTJ[10] = {0, 1, 2, 3, 1, 2, 3, 2, 3, 3};

__global__ __launch_bounds__(256) void gemm_dup(
    const unsigned short* __restrict__ ma, const unsigned short* __restrict__ pb,
    const int* __restrict__ cnt, float* __restrict__ dpart)
{
    const int b = blockIdx.y;
    int K = cnt[b]; if (K > KCAP) K = KCAP;
    const int p = blockIdx.x;
    const int I0 = cTI[p] * 64, J0 = cTJ[p] * 64;
    const float wgt = (I0 == J0) ? 1.f : 2.f;
    __shared__ unsigned short maI[32][64], pbI[32][64], maJ[32][64], pbJ[32][64];
    const int tid = threadIdx.x;
    const int lr = tid >> 3, lc = (tid & 7) * 8;
    const int tx = tid & 15, ty = tid >> 4;
    const size_t bb = (size_t)b * KCAP * 256;
    float cIJ[4][4] = {};   // cIJ[r][c] = ec[I0+ty*4+r][J0+tx*4+c]
    float cJI[4][4] = {};   // cJI[r][c] = ec[J0+tx*4+c][I0+ty*4+r]

    for (int k0 = 0; k0 < K; k0 += 32) {
        const int kr = k0 + lr;
        uint4 vai = make_uint4(0,0,0,0), vbi = vai, vaj = vai, vbj = vai;
        if (kr < K) {
            size_t rb = bb + (size_t)kr * 256;
            vai = *(const uint4*)(ma + rb + I0 + lc);
            vbi = *(const uint4*)(pb + rb + I0 + lc);
            vaj = *(const uint4*)(ma + rb + J0 + lc);
            vbj = *(const uint4*)(pb + rb + J0 + lc);
        }
        __syncthreads();
        *(uint4*)&maI[lr][lc] = vai; *(uint4*)&pbI[lr][lc] = vbi;
        *(uint4*)&maJ[lr][lc] = vaj; *(uint4*)&pbJ[lr][lc] = vbj;
        __syncthreads();
        for (int kk = 0; kk < 32; ++kk) {
            uint2 uai = *(const uint2*)&maI[kk][ty * 4];
            uint2 ubj = *(const uint2*)&pbJ[kk][tx * 4];
            uint2 uaj = *(const uint2*)&maJ[kk][tx * 4];
            uint2 ubi = *(const uint2*)&pbI[kk][ty * 4];
            float ai0 = bflo(uai.x), ai1 = bfhi(uai.x), ai2 = bflo(uai.y), ai3 = bfhi(uai.y);
            float bj0 = bflo(ubj.x), bj1 = bfhi(ubj.x), bj2 = bflo(ubj.y), bj3 = bfhi(ubj.y);
            float aj0 = bflo(uaj.x), aj1 = bfhi(uaj.x), aj2 = bflo(uaj.y), aj3 = bfhi(uaj.y);
            float bi0 = bflo(ubi.x), bi1 = bfhi(ubi.x), bi2 = bflo(ubi.y), bi3 = bfhi(ubi.y);
            cIJ[0][0] += ai0 * bj0; cIJ[0][1] += ai0 * bj1; cIJ[0][2] += ai0 * bj2; cIJ[0][3] += ai0 * bj3;
            cIJ[1][0] += ai1 * bj0; cIJ[1][1] += ai1 * bj1; cIJ[1][2] += ai1 * bj2; cIJ[1][3] += ai1 * bj3;
            cIJ[2][0] += ai2 * bj0; cIJ[2][1] += ai2 * bj1; cIJ[2][2] += ai2 * bj2; cIJ[2][3] += ai2 * bj3;
            cIJ[3][0] += ai3 * bj0; cIJ[3][1] += ai3 * bj1; cIJ[3][2] += ai3 * bj2; cIJ[3][3] += ai3 * bj3;
            cJI[0][0] += bi0 * aj0; cJI[0][1] += bi0 * aj1; cJI[0][2] += bi0 * aj2; cJI[0][3] += bi0 * aj3;
            cJI[1][0] += bi1 * aj0; cJI[1][1] += bi1 * aj1; cJI[1][2] += bi1 * aj2; cJI[1][3] += bi1 * aj3;
            cJI[2][0] += bi2 * aj0; cJI[2][1] += bi2 * aj1; cJI[2][2] += bi2 * aj2; cJI[2][3] += bi2 * aj3;
            cJI[3][0] += bi3 * aj0; cJI[3][1] += bi3 * aj1; cJI[3][2] += bi3 * aj2; cJI[3][3] += bi3 * aj3;
        }
    }
    // cJI[r][c] currently = ec[J0+tx4+c][I0+ty4+r] with c indexing aj, r indexing bi. Pair up:
    float ssum = 0.f;
#pragma unroll
    for (int r = 0; r < 4; ++r)
#pragma unroll
        for (int c = 0; c < 4; ++c) {
            float v = cIJ[r][c] + cJI[r][c] - 1.f;
            if (v > 0.f) ssum += v * v;
        }
    ssum *= wgt;
    ssum = wsum(ssum);
    __shared__ float red[4];
    if ((tid & 63) == 0) red[tid >> 6] = ssum;
    __syncthreads();
    if (tid == 0) dpart[b * 10 + p] = red[0] + red[1] + red[2] + red[3];
}

__global__ void finalize_kernel(const float* __restrict__ bpart,
                                const float* __restrict__ dpart,
                                float* __restrict__ out)
{
    const int lane = threadIdx.x;  // 64 threads; lane == batch index
    float v0 = bpart[lane * 8 + 0], v1 = bpart[lane * 8 + 1];
    float v2 = bpart[lane * 8 + 2], v3 = bpart[lane * 8 + 3];
    float v4 = bpart[lane * 8 + 4], v5 = bpart[lane * 8 + 5];
    float v6 = bpart[lane * 8 + 6], v7 = bpart[lane * 8 + 7];
    float tot_ce   = wsum(v0);
    float tot_mask = wsum(v1);
    float tot_cea  = wsum(v2);
    float tot_ceb  = wsum(v3);
    float tot_val  = wsum(v4);
    float tot_dot  = wsum(v5);
    float g = wsum(__expf(-v6) + __expf(-v7)) * (1.f / 64.f);
    float d = 0.f;
#pragma unroll
    for (int i = 0; i < 10; ++i) d += dpart[lane * 10 + i];
    float dsum = wsum(d);
    if (lane == 0) {
        float denom = tot_mask + 1e-8f;
        float type_loss = tot_ce / 65536.f;
        float node = 0.5f * (tot_cea / denom + tot_ceb / denom);
        float value = tot_val / denom;
        float self = tot_dot / denom;
        float dup = dsum / (64.f * 256.f * 256.f);
        out[0] = 1.0f * type_loss + 0.5f * node + 1.0f * value
               + 2.0f * self + 1.0f * dup + 0.5f * g;
    }
}

extern "C" void kernel_launch(void* const* d_in, const int* in_sizes, int n_in,
                              void* d_out, int out_size, void* d_ws, size_t ws_size,
                              hipStream_t stream)
{
    const float* tl   = (const float*)d_in[0];
    const float* al   = (const float*)d_in[1];
    const float* bl   = (const float*)d_in[2];
    const float* vals = (const float*)d_in[3];
    const float* seq  = (const float*)d_in[4];

    char* ws = (char*)d_ws;
    int*   cnt     = (int*)ws;
    short* slotmap = (short*)(ws + SLOT_OFF);
    float* part    = (float*)(ws + PART_OFF);
    float* bpart   = (float*)(ws + BPART_OFF);
    float* dpart   = (float*)(ws + DPART_OFF);
    unsigned short* ma = (unsigned short*)(ws + MA_OFF);
    unsigned short* pb = (unsigned short*)(ws + PB_OFF);

    scan_kernel<<<64, 256, 0, stream>>>(seq, cnt, slotmap);
    stats_kernel<<<4096, 256, 0, stream>>>(tl, al, bl, vals, seq, slotmap,
                                           part, ma, pb);
    reduce_kernel<<<64, 64, 0, stream>>>(part, bpart);
    dim3 gg(10, 64);
    gemm_dup<<<gg, 256, 0, stream>>>(ma, pb, cnt, dpart);
    finalize_kernel<<<1, 64, 0, stream>>>(bpart, dpart, (float*)d_out);
}

// Round 7
// 79.251 us; speedup vs baseline: 4.2604x; 1.1442x over previous
//
#include <hip/hip_runtime.h>
#include <hip/hip_bf16.h>
#include <math.h>

#define TT 1024
#define NTYPE 16
#define NNODE 256
#define KCAP 512   // compacted masked rows per batch (expected ~192; 26 sigma headroom)

// ws layout (bytes):
//   0        : cnt[64] int
//   1024     : slotmap[64][1024] short          128 KB
//   132096   : part[4096][8] f32                128 KB
//   263168   : bpart[64][8] f32                 2 KB
//   265216   : dpart[64][10] f32                2.5 KB
//   1048576  : ma [64][KCAP][256] f16           16 MB
//   +16M     : pb [64][KCAP][256] f16           16 MB
#define SLOT_OFF  1024
#define PART_OFF  132096
#define BPART_OFF 263168
#define DPART_OFF 265216
#define MA_OFF    1048576ll
#define PB_OFF    (MA_OFF + 64ll*KCAP*256*2)

typedef __fp16 h2 __attribute__((ext_vector_type(2)));
typedef __fp16 h4 __attribute__((ext_vector_type(4)));

__device__ __forceinline__ float wsum(float v) {
    for (int o = 32; o > 0; o >>= 1) v += __shfl_xor(v, o);
    return v;
}
__device__ __forceinline__ float gsum(float v) {   // 16-lane group sum
    v += __shfl_xor(v, 8); v += __shfl_xor(v, 4);
    v += __shfl_xor(v, 2); v += __shfl_xor(v, 1);
    return v;
}
__device__ __forceinline__ float gmax(float v) {   // 16-lane group max
    v = fmaxf(v, __shfl_xor(v, 8)); v = fmaxf(v, __shfl_xor(v, 4));
    v = fmaxf(v, __shfl_xor(v, 2)); v = fmaxf(v, __shfl_xor(v, 1));
    return v;
}
__device__ __forceinline__ unsigned pkh(float x, float y) {  // pack 2 f32 -> 2 f16
    h2 r = __builtin_amdgcn_cvt_pkrtz(x, y);
    union { h2 h; unsigned u; } c; c.h = r; return c.u;
}
__device__ __forceinline__ float fdot2(h2 a, h2 b, float c) {
#if __has_builtin(__builtin_amdgcn_fdot2)
    return __builtin_amdgcn_fdot2(a, b, c, false);
#else
    return c + (float)a[0] * (float)b[0] + (float)a[1] * (float)b[1];
#endif
}
__device__ __forceinline__ float sel4(float4 v, int e) {
    float x = (e & 1) ? v.y : v.x;
    float y = (e & 1) ? v.w : v.z;
    return (e & 2) ? y : x;
}
__device__ __forceinline__ float sel16(float4 v0, float4 v1, float4 v2, float4 v3,
                                       int j, int e) {
    float s0 = sel4(v0, e), s1 = sel4(v1, e), s2 = sel4(v2, e), s3 = sel4(v3, e);
    float c01 = (j & 1) ? s1 : s0;
    float c23 = (j & 1) ? s3 : s2;
    return (j & 2) ? c23 : c01;
}
__device__ __forceinline__ float max16(float4 a0, float4 a1, float4 a2, float4 a3) {
    float m0 = fmaxf(fmaxf(a0.x, a0.y), fmaxf(a0.z, a0.w));
    float m1 = fmaxf(fmaxf(a1.x, a1.y), fmaxf(a1.z, a1.w));
    float m2 = fmaxf(fmaxf(a2.x, a2.y), fmaxf(a2.z, a2.w));
    float m3 = fmaxf(fmaxf(a3.x, a3.y), fmaxf(a3.z, a3.w));
    return fmaxf(fmaxf(m0, m1), fmaxf(m2, m3));
}

// ---- deterministic compaction slots: per-batch prefix sum of the mask ----
__global__ __launch_bounds__(256) void scan_kernel(const float* __restrict__ seq,
                                                   int* __restrict__ cnt,
                                                   short* __restrict__ slotmap)
{
    const int b = blockIdx.x;
    const int tid = threadIdx.x;
    const int lane = tid & 63, w = tid >> 6;
    const int t0 = tid * 4;
    int m0 = 0, m1 = 0, m2 = 0, m3 = 0;
    {
        int tt;
        tt = (int)seq[((size_t)b * TT + t0 + 1) * 4];               m0 = (tt >= 3 && tt <= 5);
        tt = (int)seq[((size_t)b * TT + t0 + 2) * 4];               m1 = (tt >= 3 && tt <= 5);
        tt = (int)seq[((size_t)b * TT + t0 + 3) * 4];               m2 = (tt >= 3 && tt <= 5);
        if (t0 + 3 < TT - 1) {
            tt = (int)seq[((size_t)b * TT + t0 + 4) * 4];           m3 = (tt >= 3 && tt <= 5);
        }
    }
    int lc = m0 + m1 + m2 + m3;
    int inc = lc;
    for (int o = 1; o < 64; o <<= 1) {
        int v = __shfl_up(inc, o);
        if (lane >= o) inc += v;
    }
    __shared__ int wtot[4];
    if (lane == 63) wtot[w] = inc;
    __syncthreads();
    int woff = 0;
    for (int i = 0; i < 4; ++i) woff += (i < w) ? wtot[i] : 0;
    int run = woff + inc - lc;
    if (m0) { slotmap[(size_t)b * TT + t0 + 0] = (short)run; ++run; }
    if (m1) { slotmap[(size_t)b * TT + t0 + 1] = (short)run; ++run; }
    if (m2) { slotmap[(size_t)b * TT + t0 + 2] = (short)run; ++run; }
    if (m3) { slotmap[(size_t)b * TT + t0 + 3] = (short)run; ++run; }
    if (tid == 255) cnt[b] = woff + inc;
}

// ---- fused per-row stats: 16-lane group per row, 4 rows per wave ----
__global__ __launch_bounds__(256) void stats_kernel(
    const float* __restrict__ tl, const float* __restrict__ al,
    const float* __restrict__ bl, const float* __restrict__ vals,
    const float* __restrict__ seq, const short* __restrict__ slotmap,
    float* __restrict__ part,
    unsigned short* __restrict__ ma, unsigned short* __restrict__ pb)
{
    const int tid = threadIdx.x;
    const int w = tid >> 6, lane = tid & 63;
    const int s = lane & 15;                       // sublane within 16-lane group
    const int rowbase = blockIdx.x * 16 + w * 4;
    const int row = rowbase + (lane >> 4);
    const int b = row >> 10, t = row & 1023;

    // shifted target (group-uniform)
    float4 tgt = make_float4(0.f, 0.f, 0.f, 0.f);
    if (t < TT - 1) tgt = *(const float4*)(seq + (size_t)(row + 1) * 4);
    const int   t_type = (int)tgt.x;
    const int   t_a    = (int)tgt.y;
    const int   t_b    = (int)tgt.z;
    const float t_val  = tgt.w;
    const float mask   = (t_type >= 3 && t_type <= 5) ? 1.f : 0.f;

    // ---- type softmax: exactly 1 logit per sublane ----
    float tlv = tl[(size_t)rowbase * 16 + lane];
    float tmx = gmax(tlv);
    float te  = __expf(tlv - tmx);
    float tsum = gsum(te);
    float tcs  = gsum((s >= 3 && s <= 5) ? te : 0.f);
    float p_comp = tcs / tsum;
    float ce_type = __logf(tsum) + tmx - __shfl(tlv, (lane & 48) + t_type);

    // ---- node a: 16 logits per sublane (4 x float4, stride-64 chunks) ----
    const float* arow = al + (size_t)row * 256;
    float4 a0 = *(const float4*)(arow + s * 4);
    float4 a1 = *(const float4*)(arow + s * 4 + 64);
    float4 a2 = *(const float4*)(arow + s * 4 + 128);
    float4 a3 = *(const float4*)(arow + s * 4 + 192);
    const float* brow = bl + (size_t)row * 256;
    float4 b0 = *(const float4*)(brow + s * 4);
    float4 b1 = *(const float4*)(brow + s * 4 + 64);
    float4 b2 = *(const float4*)(brow + s * 4 + 128);
    float4 b3 = *(const float4*)(brow + s * 4 + 192);

    // CE gathers on raw logits (issued early; independent of reductions)
    const int ja = t_a >> 6, sa = (t_a >> 2) & 15, ea = t_a & 3;
    const int jb = t_b >> 6, sb = (t_b >> 2) & 15, eb = t_b & 3;
    float ga = __shfl(sel16(a0, a1, a2, a3, ja, ea), (lane & 48) + sa);
    float gb = __shfl(sel16(b0, b1, b2, b3, jb, eb), (lane & 48) + sb);

    float amx = gmax(max16(a0, a1, a2, a3));
    float bmx = gmax(max16(b0, b1, b2, b3));

    float ea0x = __expf(a0.x - amx), ea0y = __expf(a0.y - amx), ea0z = __expf(a0.z - amx), ea0w = __expf(a0.w - amx);
    float ea1x = __expf(a1.x - amx), ea1y = __expf(a1.y - amx), ea1z = __expf(a1.z - amx), ea1w = __expf(a1.w - amx);
    float ea2x = __expf(a2.x - amx), ea2y = __expf(a2.y - amx), ea2z = __expf(a2.z - amx), ea2w = __expf(a2.w - amx);
    float ea3x = __expf(a3.x - amx), ea3y = __expf(a3.y - amx), ea3z = __expf(a3.z - amx), ea3w = __expf(a3.w - amx);
    float eb0x = __expf(b0.x - bmx), eb0y = __expf(b0.y - bmx), eb0z = __expf(b0.z - bmx), eb0w = __expf(b0.w - bmx);
    float eb1x = __expf(b1.x - bmx), eb1y = __expf(b1.y - bmx), eb1z = __expf(b1.z - bmx), eb1w = __expf(b1.w - bmx);
    float eb2x = __expf(b2.x - bmx), eb2y = __expf(b2.y - bmx), eb2z = __expf(b2.z - bmx), eb2w = __expf(b2.w - bmx);
    float eb3x = __expf(b3.x - bmx), eb3y = __expf(b3.y - bmx), eb3z = __expf(b3.z - bmx), eb3w = __expf(b3.w - bmx);

    float lsa = ((ea0x + ea0y) + (ea0z + ea0w)) + ((ea1x + ea1y) + (ea1z + ea1w))
              + ((ea2x + ea2y) + (ea2z + ea2w)) + ((ea3x + ea3y) + (ea3z + ea3w));
    float lsb = ((eb0x + eb0y) + (eb0z + eb0w)) + ((eb1x + eb1y) + (eb1z + eb1w))
              + ((eb2x + eb2y) + (eb2z + eb2w)) + ((eb3x + eb3y) + (eb3z + eb3w));
    float asum = gsum(lsa);
    float bsum = gsum(lsb);
    float ainv = 1.f / asum, binv = 1.f / bsum;

    float ce_a = __logf(asum) + amx - ga;
    float ce_b = __logf(bsum) + bmx - gb;

    // selfloop dot: sum(ea*eb) * ainv * binv
    float dl = ((ea0x * eb0x + ea0y * eb0y) + (ea0z * eb0z + ea0w * eb0w))
             + ((ea1x * eb1x + ea1y * eb1y) + (ea1z * eb1z + ea1w * eb1w))
             + ((ea2x * eb2x + ea2y * eb2y) + (ea2z * eb2z + ea2w * eb2w))
             + ((ea3x * eb3x + ea3y * eb3y) + (ea3z * eb3z + ea3w * eb3w));
    float dot = gsum(dl) * ainv * binv;

    // gnd: p_a[0],p_a[1],p_b[0],p_b[1] live on sublane 0 (elements 0,1)
    float s0c = ((ea0x * ainv) + (eb0x * binv)) * p_comp;
    float s1c = ((ea0y * ainv) + (eb0y * binv)) * p_comp;

    // value loss (group-uniform)
    float pv = vals[row];
    float vloss = mask * (pv - t_val) * (pv - t_val);

    // ---- compacted f16 prob rows ----
    if (mask > 0.f) {
        int slot = slotmap[row];
        if (slot < KCAP) {
            size_t base = ((size_t)b * KCAP + slot) * 256 + s * 4;
            *(uint2*)(ma + base)       = make_uint2(pkh(ea0x * ainv, ea0y * ainv), pkh(ea0z * ainv, ea0w * ainv));
            *(uint2*)(ma + base + 64)  = make_uint2(pkh(ea1x * ainv, ea1y * ainv), pkh(ea1z * ainv, ea1w * ainv));
            *(uint2*)(ma + base + 128) = make_uint2(pkh(ea2x * ainv, ea2y * ainv), pkh(ea2z * ainv, ea2w * ainv));
            *(uint2*)(ma + base + 192) = make_uint2(pkh(ea3x * ainv, ea3y * ainv), pkh(ea3z * ainv, ea3w * ainv));
            *(uint2*)(pb + base)       = make_uint2(pkh(eb0x * binv, eb0y * binv), pkh(eb0z * binv, eb0w * binv));
            *(uint2*)(pb + base + 64)  = make_uint2(pkh(eb1x * binv, eb1y * binv), pkh(eb1z * binv, eb1w * binv));
            *(uint2*)(pb + base + 128) = make_uint2(pkh(eb2x * binv, eb2y * binv), pkh(eb2z * binv, eb2w * binv));
            *(uint2*)(pb + base + 192) = make_uint2(pkh(eb3x * binv, eb3y * binv), pkh(eb3z * binv, eb3w * binv));
        }
    }

    // ---- reduce 8 scalars: group-leader only, then xor16+xor32 across groups ----
    float r0 = (s == 0) ? ce_type       : 0.f;
    float r1 = (s == 0) ? mask          : 0.f;
    float r2 = (s == 0) ? mask * ce_a   : 0.f;
    float r3 = (s == 0) ? mask * ce_b   : 0.f;
    float r4 = (s == 0) ? vloss         : 0.f;
    float r5 = (s == 0) ? mask * dot    : 0.f;
    float r6 = (s == 0) ? s0c           : 0.f;
    float r7 = (s == 0) ? s1c           : 0.f;
#define XR(v) v += __shfl_xor(v, 16); v += __shfl_xor(v, 32);
    XR(r0) XR(r1) XR(r2) XR(r3) XR(r4) XR(r5) XR(r6) XR(r7)
#undef XR
    __shared__ float red[4][8];
    if (lane == 0) {
        red[w][0] = r0; red[w][1] = r1; red[w][2] = r2; red[w][3] = r3;
        red[w][4] = r4; red[w][5] = r5; red[w][6] = r6; red[w][7] = r7;
    }
    __syncthreads();
    if (tid < 8) {
        part[(size_t)blockIdx.x * 8 + tid] =
            red[0][tid] + red[1][tid] + red[2][tid] + red[3][tid];
    }
}

// ---- per-batch reduction of 64 block partials ----
__global__ __launch_bounds__(64) void reduce_kernel(const float* __restrict__ part,
                                                    float* __restrict__ bpart)
{
    const int b = blockIdx.x;
    const float* p = part + ((size_t)b * 64 + threadIdx.x) * 8;
    float v0 = wsum(p[0]), v1 = wsum(p[1]), v2 = wsum(p[2]), v3 = wsum(p[3]);
    float v4 = wsum(p[4]), v5 = wsum(p[5]), v6 = wsum(p[6]), v7 = wsum(p[7]);
    if (threadIdx.x == 0) {
        float* o = bpart + b * 8;
        o[0] = v0; o[1] = v1; o[2] = v2; o[3] = v3;
        o[4] = v4; o[5] = v5; o[6] = v6; o[7] = v7;
    }
}

// ---- fused ec GEMM + dup penalty: 64x64 tile pairs, f16 dot2, no ec materialization ----
// LDS layout per array: [8 kgroups][64 cols] of h4 (4 consecutive k per col),
// byte addr = (g*512 + col*8) ^ (((col>>3)&7)<<4)  -> conflict-free staging writes,
// <=2-way (free) compute reads, 8B alignment preserved (XOR touches bits 4..6 only).
__constant__ int cTI[10] = {0, 1, 2, 3, 0, 0, 0, 1, 1, 2};
__constant__ int cTJ[10] = {0, 1, 2, 3, 1, 2, 3, 2, 3, 3};

__global__ __launch_bounds__(256) void gemm_dup(
    const unsigned short* __restrict__ ma, const unsigned short* __restrict__ pb,
    const int* __restrict__ cnt, float* __restrict__ dpart)
{
    __shared__ char lds0[4096], lds1[4096], lds2[4096], lds3[4096];
    const int b = blockIdx.y;
    int K = cnt[b]; if (K > KCAP) K = KCAP;
    const int p = blockIdx.x;
    const int I0 = cTI[p] * 64, J0 = cTJ[p] * 64;
    const float wgt = (I0 == J0) ? 1.f : 2.f;
    const int tid = threadIdx.x;
    const int lr = tid >> 3, lc = (tid & 7) * 8;
    const int tx = tid & 15, ty = tid >> 4;
    const size_t bb = (size_t)b * KCAP * 256;
    float cIJ[4][4] = {};   // cIJ[r][c] = ec[I0+ty*4+r][J0+tx*4+c]
    float cJI[4][4] = {};   // cJI[r][c] = ec[J0+tx*4+c][I0+ty*4+r]

    for (int k0 = 0; k0 < K; k0 += 32) {
        const int kr = k0 + lr;
        uint4 vai = make_uint4(0,0,0,0), vbi = vai, vaj = vai, vbj = vai;
        if (kr < K) {
            size_t rb = bb + (size_t)kr * 256;
            vai = *(const uint4*)(ma + rb + I0 + lc);
            vbi = *(const uint4*)(pb + rb + I0 + lc);
            vaj = *(const uint4*)(ma + rb + J0 + lc);
            vbj = *(const uint4*)(pb + rb + J0 + lc);
        }
        __syncthreads();
        {
            const int g = lr >> 2;
            const int ko = (lr & 3) * 2;
            const __fp16* hai = (const __fp16*)&vai;
            const __fp16* hbi = (const __fp16*)&vbi;
            const __fp16* haj = (const __fp16*)&vaj;
            const __fp16* hbj = (const __fp16*)&vbj;
#pragma unroll
            for (int j = 0; j < 8; ++j) {
                const int col = lc + j;
                const int off = ((g * 512 + col * 8) ^ (((col >> 3) & 7) << 4)) + ko;
                *(__fp16*)(lds0 + off) = hai[j];
                *(__fp16*)(lds1 + off) = hbi[j];
                *(__fp16*)(lds2 + off) = haj[j];
                *(__fp16*)(lds3 + off) = hbj[j];
            }
        }
        __syncthreads();
#pragma unroll
        for (int g = 0; g < 8; ++g) {
            h2 aIl[4], aIh[4], bIl[4], bIh[4], aJl[4], aJh[4], bJl[4], bJh[4];
#pragma unroll
            for (int r = 0; r < 4; ++r) {
                const int ca = ty * 4 + r, cb = tx * 4 + r;
                const int offa = (g * 512 + ca * 8) ^ (((ca >> 3) & 7) << 4);
                const int offb = (g * 512 + cb * 8) ^ (((cb >> 3) & 7) << 4);
                h4 vA = *(const h4*)(lds0 + offa);
                h4 vB = *(const h4*)(lds1 + offa);
                h4 vC = *(const h4*)(lds2 + offb);
                h4 vD = *(const h4*)(lds3 + offb);
                aIl[r] = __builtin_shufflevector(vA, vA, 0, 1); aIh[r] = __builtin_shufflevector(vA, vA, 2, 3);
                bIl[r] = __builtin_shufflevector(vB, vB, 0, 1); bIh[r] = __builtin_shufflevector(vB, vB, 2, 3);
                aJl[r] = __builtin_shufflevector(vC, vC, 0, 1); aJh[r] = __builtin_shufflevector(vC, vC, 2, 3);
                bJl[r] = __builtin_shufflevector(vD, vD, 0, 1); bJh[r] = __builtin_shufflevector(vD, vD, 2, 3);
            }
#pragma unroll
            for (int r = 0; r < 4; ++r)
#pragma unroll
                for (int c = 0; c < 4; ++c) {
                    cIJ[r][c] = fdot2(aIl[r], bJl[c], cIJ[r][c]);
                    cIJ[r][c] = fdot2(aIh[r], bJh[c], cIJ[r][c]);
                    cJI[r][c] = fdot2(bIl[r], aJl[c], cJI[r][c]);
                    cJI[r][c] = fdot2(bIh[r], aJh[c], cJI[r][c]);
                }
        }
    }
    float ssum = 0.f;
#pragma unroll
    for (int r = 0; r < 4; ++r)
#pragma unroll
        for (int c = 0; c < 4; ++c) {
            float v = cIJ[r][c] + cJI[r][c] - 1.f;
            if (v > 0.f) ssum += v * v;
        }
    ssum *= wgt;
    ssum = wsum(ssum);
    __shared__ float red[4];
    if ((tid & 63) == 0) red[tid >> 6] = ssum;
    __syncthreads();
    if (tid == 0) dpart[b * 10 + p] = red[0] + red[1] + red[2] + red[3];
}

__global__ void finalize_kernel(const float* __restrict__ bpart,
                                const float* __restrict__ dpart,
                                float* __restrict__ out)
{
    const int lane = threadIdx.x;  // 64 threads; lane == batch index
    float v0 = bpart[lane * 8 + 0], v1 = bpart[lane * 8 + 1];
    float v2 = bpart[lane * 8 + 2], v3 = bpart[lane * 8 + 3];
    float v4 = bpart[lane * 8 + 4], v5 = bpart[lane * 8 + 5];
    float v6 = bpart[lane * 8 + 6], v7 = bpart[lane * 8 + 7];
    float tot_ce   = wsum(v0);
    float tot_mask = wsum(v1);
    float tot_cea  = wsum(v2);
    float tot_ceb  = wsum(v3);
    float tot_val  = wsum(v4);
    float tot_dot  = wsum(v5);
    float g = wsum(__expf(-v6) + __expf(-v7)) * (1.f / 64.f);
    float d = 0.f;
#pragma unroll
    for (int i = 0; i < 10; ++i) d += dpart[lane * 10 + i];
    float dsum = wsum(d);
    if (lane == 0) {
        float denom = tot_mask + 1e-8f;
        float type_loss = tot_ce / 65536.f;
        float node = 0.5f * (tot_cea / denom + tot_ceb / denom);
        float value = tot_val / denom;
        float self = tot_dot / denom;
        float dup = dsum / (64.f * 256.f * 256.f);
        out[0] = 1.0f * type_loss + 0.5f * node + 1.0f * value
               + 2.0f * self + 1.0f * dup + 0.5f * g;
    }
}

extern "C" void kernel_launch(void* const* d_in, const int* in_sizes, int n_in,
                              void* d_out, int out_size, void* d_ws, size_t ws_size,
                              hipStream_t stream)
{
    const float* tl   = (const float*)d_in[0];
    const float* al   = (const float*)d_in[1];
    const float* bl   = (const float*)d_in[2];
    const float* vals = (const float*)d_in[3];
    const float* seq  = (const float*)d_in[4];

    char* ws = (char*)d_ws;
    int*   cnt     = (int*)ws;
    short* slotmap = (short*)(ws + SLOT_OFF);
    float* part    = (float*)(ws + PART_OFF);
    float* bpart   = (float*)(ws + BPART_OFF);
    float* dpart   = (float*)(ws + DPART_OFF);
    unsigned short* ma = (unsigned short*)(ws + MA_OFF);
    unsigned short* pb = (unsigned short*)(ws + PB_OFF);

    scan_kernel<<<64, 256, 0, stream>>>(seq, cnt, slotmap);
    stats_kernel<<<4096, 256, 0, stream>>>(tl, al, bl, vals, seq, slotmap,
                                           part, ma, pb);
    reduce_kernel<<<64, 64, 0, stream>>>(part, bpart);
    dim3 gg(10, 64);
    gemm_dup<<<gg, 256, 0, stream>>>(ma, pb, cnt, dpart);
    finalize_kernel<<<1, 64, 0, stream>>>(bpart, dpart, (float*)d_out);
}